// Round 5
// baseline (185.186 us; speedup 1.0000x reference)
//
#include <hip/hip_runtime.h>

// MicrotubuleDynamicsModel fused forward, round 5 structure:
//  - prep_w: split Wg[0..2]+Wd1 into hi/lo bf16 MFMA A-fragments in d_ws.
//  - mt_fwd: 1 sample/block, 128 threads (2 waves = 2 node-halves).
//    x state lives ONLY as bf16 split pair (bh/bl) in registers (B-frag layout).
//    Per layer: h = x@W^T via MFMA (3-pass split) -> write h to quad-transposed
//    LDS mirror -> gather t = A@h (zero addr-VALU, conflict-free-ish) ->
//    epilogue x += relu(t+b) with reconstruct+resplit in registers.
//    LDS = 32 quads x 53 nodes x 16B = 27136B -> 6 blocks/CU.

typedef __attribute__((ext_vector_type(2)))  float  f32x2;
typedef __attribute__((ext_vector_type(4)))  float  f32x4;
typedef __attribute__((ext_vector_type(16))) float  f32x16;
typedef __attribute__((ext_vector_type(8)))  __bf16 bf16x8;

#define MFMA(a, b, c) __builtin_amdgcn_mfma_f32_32x32x16_bf16((a), (b), (c), 0, 0, 0)

#define QSTR 53          // node stride inside a quad-plane
#define QP   (QSTR * 4)  // dwords per quad-plane = 212

struct bfpair { __bf16 h, l; };
__device__ __forceinline__ bfpair splitf(float f) {
    bfpair p;
    p.h = (__bf16)f;               // RTN
    p.l = (__bf16)(f - (float)p.h);
    return p;
}

// ---------------- prep: split + fragment-pack W into workspace ----------------
// frag tid = (((L*8+kc)*4+ot)*2+hi)*32+lane ; elems = W[L][ot*32+lane][kc*16+hi*8+e]
__global__ __launch_bounds__(256) void prep_w(
    const float* __restrict__ Wg, const float* __restrict__ Wd1,
    __bf16* __restrict__ ws)
{
    const int tid  = blockIdx.x * 256 + threadIdx.x;   // 0..8191
    const int lane = tid & 31;
    const int hi   = (tid >> 5) & 1;
    const int ot   = (tid >> 6) & 3;
    const int kc   = (tid >> 8) & 7;
    const int L    = tid >> 11;
    const float* src = ((L < 3) ? (Wg + L * 16384) : Wd1)
                     + (ot * 32 + lane) * 128 + kc * 16 + hi * 8;
    const f32x4 v0 = *(const f32x4*)(src);
    const f32x4 v1 = *(const f32x4*)(src + 4);
    bf16x8 h8, l8;
    #pragma unroll
    for (int e = 0; e < 4; ++e) {
        bfpair p0 = splitf(v0[e]); h8[e]   = p0.h; l8[e]   = p0.l;
        bfpair p1 = splitf(v1[e]); h8[4+e] = p1.h; l8[4+e] = p1.l;
    }
    ((bf16x8*)ws)[tid]        = h8;   // Ph
    ((bf16x8*)ws)[8192 + tid] = l8;   // Pl
}

// ------------------------------- main kernel -------------------------------
__global__ __launch_bounds__(128, 3) void mt_fwd(
    const float* __restrict__ q,   const float* __restrict__ Win, const float* __restrict__ bin,
    const float* __restrict__ bg,  const float* __restrict__ bd1,
    const float* __restrict__ Wd2, const float* __restrict__ bd2,
    const bf16x8* __restrict__ Ph, float* __restrict__ out)
{
    __shared__ __attribute__((aligned(16))) float hs[32 * QP];   // 27136 B

    const int t    = threadIdx.x;
    const int nt   = t >> 6;            // wave: node-tile 0/1
    const int l    = t & 63;
    const int lane = l & 31;
    const int hi   = l >> 5;
    const int n    = nt * 32 + lane;    // this lane's node (col in D)
    const int nc   = (n < 52) ? n : 0;
    const int samp = blockIdx.x;
    const bf16x8* Pl = Ph + 8192;

    // LDS dword bases
    const int wbase = n * 4 + hi * QP;       // D-quad writes: + (ot*8+2j)*QP
    const int rbase = nc * 4 + hi * 2 * QP;  // B-quad reads:  + (kc*4+d)*QP

    // ---- closed-form GCN neighbors (self + 2 lateral(dup x2) + <=2 chain) ----
    int nb[5]; float nw[5];
    {
        const int   fi = n >> 2, js = n & 3;
        const float dg = 5.f + (js > 0 ? 1.f : 0.f) + (js < 3 ? 1.f : 0.f);
        const float di = rsqrtf(dg);
        nb[0] = n;                          nw[0] = di * di;
        nb[1] = ((fi + 12) % 13) * 4 + js;  nw[1] = 2.f * di * di;
        nb[2] = ((fi + 1) % 13) * 4 + js;   nw[2] = 2.f * di * di;
        nb[3] = (js > 0) ? (n - 1) : 0;
        nw[3] = (js > 0) ? di * rsqrtf(6.f + (js > 1 ? 1.f : 0.f)) : 0.f;
        nb[4] = (js < 3) ? (n + 1) : 0;
        nw[4] = (js < 3) ? di * rsqrtf(6.f + (js < 2 ? 1.f : 0.f)) : 0.f;
        if (n >= 52) {
            #pragma unroll
            for (int c = 0; c < 5; ++c) { nb[c] = 0; nw[c] = 0.f; }
        }
    }
    int gb[5];
    #pragma unroll
    for (int c = 0; c < 5; ++c) gb[c] = nb[c] * 4 + hi * 2 * QP;

    bf16x8 bh[8], bl[8];   // persistent x state (B-frag layout, split)

    // ---------------- encoder: x0^T = relu(Win @ q^T + bin) ----------------
    {
        f32x4 z4; z4[0]=0.f; z4[1]=0.f; z4[2]=0.f; z4[3]=0.f;
        f32x4 u0 = z4, u1 = z4;
        if (hi == 0 && n < 52) {
            const float* qp = q + (samp * 52 + n) * 6;
            const f32x2 a = *(const f32x2*)(qp);
            const f32x2 b = *(const f32x2*)(qp + 2);
            const f32x2 c = *(const f32x2*)(qp + 4);
            u0[0]=a[0]; u0[1]=a[1]; u0[2]=b[0]; u0[3]=b[1]; u1[0]=c[0]; u1[1]=c[1];
        }
        bf16x8 qh, ql;
        #pragma unroll
        for (int e = 0; e < 4; ++e) {
            bfpair p0 = splitf(u0[e]); qh[e]   = p0.h; ql[e]   = p0.l;
            bfpair p1 = splitf(u1[e]); qh[4+e] = p1.h; ql[4+e] = p1.l;
        }

        #pragma unroll
        for (int ot = 0; ot < 4; ++ot) {
            f32x4 v0 = z4, v1 = z4;
            if (hi == 0) {
                const int o_r = ot * 32 + lane;
                const f32x2 a = *(const f32x2*)(Win + o_r * 6);
                const f32x2 b = *(const f32x2*)(Win + o_r * 6 + 2);
                const f32x2 c = *(const f32x2*)(Win + o_r * 6 + 4);
                v0[0]=a[0]; v0[1]=a[1]; v0[2]=b[0]; v0[3]=b[1]; v1[0]=c[0]; v1[1]=c[1];
            }
            bf16x8 ah, al;
            #pragma unroll
            for (int e = 0; e < 4; ++e) {
                bfpair p0 = splitf(v0[e]); ah[e]   = p0.h; al[e]   = p0.l;
                bfpair p1 = splitf(v1[e]); ah[4+e] = p1.h; al[4+e] = p1.l;
            }
            f32x16 acc;
            #pragma unroll
            for (int r = 0; r < 16; ++r) acc[r] = 0.f;
            acc = MFMA(ah, qh, acc);
            acc = MFMA(ah, ql, acc);
            acc = MFMA(al, qh, acc);
            if (n < 52) {
                #pragma unroll
                for (int j = 0; j < 4; ++j) {
                    const f32x4 bv = *(const f32x4*)(bin + ot * 32 + 8 * j + 4 * hi);
                    f32x4 v;
                    #pragma unroll
                    for (int e = 0; e < 4; ++e) v[e] = fmaxf(acc[4 * j + e] + bv[e], 0.f);
                    *(f32x4*)&hs[wbase + (ot * 8 + 2 * j) * QP] = v;
                }
            }
        }
    }
    __syncthreads();
    // read back x0 in B-frag layout, split into bh/bl
    #pragma unroll
    for (int kc = 0; kc < 8; ++kc) {
        const f32x4 a0 = *(const f32x4*)&hs[rbase + (kc * 4 + 0) * QP];
        const f32x4 a1 = *(const f32x4*)&hs[rbase + (kc * 4 + 1) * QP];
        #pragma unroll
        for (int e = 0; e < 4; ++e) {
            bfpair p0 = splitf(a0[e]); bh[kc][e]   = p0.h; bl[kc][e]   = p0.l;
            bfpair p1 = splitf(a1[e]); bh[kc][4+e] = p1.h; bl[kc][4+e] = p1.l;
        }
    }
    __syncthreads();

    // ------------------- 3 GNN layers -------------------
    #pragma unroll 1
    for (int L = 0; L < 3; ++L) {
        const int fbase = L * 2048 + hi * 32 + lane;

        // ---- h = x @ W^T (MFMA, 3-pass split) ----
        f32x16 acc[4];
        #pragma unroll
        for (int ot = 0; ot < 4; ++ot)
            #pragma unroll
            for (int r = 0; r < 16; ++r) acc[ot][r] = 0.f;

        #pragma unroll
        for (int kc = 0; kc < 8; ++kc) {
            const int fk = fbase + kc * 256;
            #pragma unroll
            for (int ot = 0; ot < 4; ++ot) {
                const bf16x8 wh = Ph[fk + ot * 64];
                const bf16x8 wl = Pl[fk + ot * 64];
                acc[ot] = MFMA(wh, bh[kc], acc[ot]);
                acc[ot] = MFMA(wh, bl[kc], acc[ot]);
                acc[ot] = MFMA(wl, bh[kc], acc[ot]);
            }
        }

        // ---- write h quads (D-layout) ----
        if (n < 52) {
            #pragma unroll
            for (int ot = 0; ot < 4; ++ot)
                #pragma unroll
                for (int j = 0; j < 4; ++j) {
                    f32x4 v = { acc[ot][4*j+0], acc[ot][4*j+1], acc[ot][4*j+2], acc[ot][4*j+3] };
                    *(f32x4*)&hs[wbase + (ot * 8 + 2 * j) * QP] = v;
                }
        }
        __syncthreads();

        // ---- gather t = A @ h (B-frag layout quads) ----
        f32x4 t0[8], t1[8];
        #pragma unroll
        for (int kc = 0; kc < 8; ++kc)
            #pragma unroll
            for (int e = 0; e < 4; ++e) { t0[kc][e] = 0.f; t1[kc][e] = 0.f; }
        #pragma unroll
        for (int c = 0; c < 5; ++c) {
            const float w = nw[c];
            const int   b = gb[c];
            #pragma unroll
            for (int kc = 0; kc < 8; ++kc) {
                const f32x4 r0 = *(const f32x4*)&hs[b + (kc * 4 + 0) * QP];
                const f32x4 r1 = *(const f32x4*)&hs[b + (kc * 4 + 1) * QP];
                t0[kc] += w * r0;
                t1[kc] += w * r1;
            }
        }
        __syncthreads();   // gather reads done before next layer's writes

        // ---- epilogue: x += relu(t + b), reconstruct + resplit in regs ----
        const float* bsrc = bg + L * 128;
        #pragma unroll
        for (int kc = 0; kc < 8; ++kc) {
            const int f0 = kc * 16 + 8 * hi;
            const f32x4 b0 = *(const f32x4*)(bsrc + f0);
            const f32x4 b1 = *(const f32x4*)(bsrc + f0 + 4);
            #pragma unroll
            for (int e = 0; e < 4; ++e) {
                {
                    const float xo = (float)bh[kc][e] + (float)bl[kc][e];
                    const float xn = xo + fmaxf(t0[kc][e] + b0[e], 0.f);
                    bfpair p = splitf(xn); bh[kc][e] = p.h; bl[kc][e] = p.l;
                }
                {
                    const float xo = (float)bh[kc][4+e] + (float)bl[kc][4+e];
                    const float xn = xo + fmaxf(t1[kc][e] + b1[e], 0.f);
                    bfpair p = splitf(xn); bh[kc][4+e] = p.h; bl[kc][4+e] = p.l;
                }
            }
        }
    }

    // ---------------- decoder-1: y = relu(x @ Wd1^T + bd1) ----------------
    {
        const int fbase = 3 * 2048 + hi * 32 + lane;
        f32x16 acc[4];
        #pragma unroll
        for (int ot = 0; ot < 4; ++ot)
            #pragma unroll
            for (int r = 0; r < 16; ++r) acc[ot][r] = 0.f;
        #pragma unroll
        for (int kc = 0; kc < 8; ++kc) {
            const int fk = fbase + kc * 256;
            #pragma unroll
            for (int ot = 0; ot < 4; ++ot) {
                const bf16x8 wh = Ph[fk + ot * 64];
                const bf16x8 wl = Pl[fk + ot * 64];
                acc[ot] = MFMA(wh, bh[kc], acc[ot]);
                acc[ot] = MFMA(wh, bl[kc], acc[ot]);
                acc[ot] = MFMA(wl, bh[kc], acc[ot]);
            }
        }
        __syncthreads();   // previous-layer gather reads are long done; reuse hs for y
        if (n < 52) {
            #pragma unroll
            for (int ot = 0; ot < 4; ++ot)
                #pragma unroll
                for (int j = 0; j < 4; ++j) {
                    const f32x4 bv = *(const f32x4*)(bd1 + ot * 32 + 8 * j + 4 * hi);
                    f32x4 v;
                    #pragma unroll
                    for (int e = 0; e < 4; ++e) v[e] = fmaxf(acc[ot][4 * j + e] + bv[e], 0.f);
                    *(f32x4*)&hs[wbase + (ot * 8 + 2 * j) * QP] = v;
                }
        }
        __syncthreads();
        #pragma unroll
        for (int kc = 0; kc < 8; ++kc) {
            const f32x4 a0 = *(const f32x4*)&hs[rbase + (kc * 4 + 0) * QP];
            const f32x4 a1 = *(const f32x4*)&hs[rbase + (kc * 4 + 1) * QP];
            #pragma unroll
            for (int e = 0; e < 4; ++e) {
                bfpair p0 = splitf(a0[e]); bh[kc][e]   = p0.h; bl[kc][e]   = p0.l;
                bfpair p1 = splitf(a1[e]); bh[kc][4+e] = p1.h; bl[kc][4+e] = p1.l;
            }
        }
    }

    // ---------------- decoder-2: out^T = Wd2 @ y^T + bd2 ----------------
    {
        f32x16 acc;
        #pragma unroll
        for (int r = 0; r < 16; ++r) acc[r] = 0.f;
        f32x4 z4; z4[0]=0.f; z4[1]=0.f; z4[2]=0.f; z4[3]=0.f;

        #pragma unroll
        for (int kc = 0; kc < 8; ++kc) {
            const int kb = kc * 16 + 8 * hi;
            f32x4 w0 = z4, w1 = z4;
            if (lane < 6) {
                const float* wp = Wd2 + lane * 128 + kb;
                w0 = *(const f32x4*)(wp);
                w1 = *(const f32x4*)(wp + 4);
            }
            bf16x8 ah, al;
            #pragma unroll
            for (int e = 0; e < 4; ++e) {
                bfpair p0 = splitf(w0[e]); ah[e]   = p0.h; al[e]   = p0.l;
                bfpair p1 = splitf(w1[e]); ah[4+e] = p1.h; al[4+e] = p1.l;
            }
            acc = MFMA(ah, bh[kc], acc);
            acc = MFMA(ah, bl[kc], acc);
            acc = MFMA(al, bh[kc], acc);
        }
        if (n < 52) {
            float* op = out + (samp * 52 + n) * 6;
            if (hi == 0) {
                #pragma unroll
                for (int r = 0; r < 4; ++r) op[r] = acc[r] + bd2[r];          // f = r
            } else {
                #pragma unroll
                for (int r = 0; r < 2; ++r) op[4 + r] = acc[r] + bd2[4 + r];  // f = 4+r
            }
        }
    }
}

extern "C" void kernel_launch(void* const* d_in, const int* in_sizes, int n_in,
                              void* d_out, int out_size, void* d_ws, size_t ws_size,
                              hipStream_t stream) {
    (void)in_sizes; (void)n_in; (void)ws_size; (void)out_size;
    const float* q   = (const float*)d_in[0];
    const float* Win = (const float*)d_in[1];
    const float* bin = (const float*)d_in[2];
    const float* Wg  = (const float*)d_in[3];
    const float* bg  = (const float*)d_in[4];
    const float* Wd1 = (const float*)d_in[5];
    const float* bd1 = (const float*)d_in[6];
    const float* Wd2 = (const float*)d_in[7];
    const float* bd2 = (const float*)d_in[8];
    float* out = (float*)d_out;

    prep_w<<<32, 256, 0, stream>>>(Wg, Wd1, (__bf16*)d_ws);
    mt_fwd<<<4096, 128, 0, stream>>>(q, Win, bin, bg, bd1, Wd2, bd2,
                                     (const bf16x8*)d_ws, out);
}

// Round 6
// 159.375 us; speedup vs baseline: 1.1620x; 1.1620x over previous
//
#include <hip/hip_runtime.h>

// MicrotubuleDynamicsModel fused forward, round 6:
// Round-5 structure (aggregate-after-multiply, x state as bf16 split pair in
// regs, quad-transposed LDS h-mirror) with the register schedule fixed to
// avoid scratch spills:
//   - matmul phase processes ot in PAIRS (2x f32x16 acc = 32 VGPR, not 64)
//   - gather+epilogue fused per kc (no t0[8]/t1[8] arrays)
// Peak VGPR ~125 -> no spill at 3 waves/SIMD. LDS 27136B -> 6 blocks/CU.

typedef __attribute__((ext_vector_type(2)))  float  f32x2;
typedef __attribute__((ext_vector_type(4)))  float  f32x4;
typedef __attribute__((ext_vector_type(16))) float  f32x16;
typedef __attribute__((ext_vector_type(8)))  __bf16 bf16x8;

#define MFMA(a, b, c) __builtin_amdgcn_mfma_f32_32x32x16_bf16((a), (b), (c), 0, 0, 0)

#define QSTR 53          // node stride inside a quad-plane
#define QP   (QSTR * 4)  // dwords per quad-plane = 212

struct bfpair { __bf16 h, l; };
__device__ __forceinline__ bfpair splitf(float f) {
    bfpair p;
    p.h = (__bf16)f;               // RTN
    p.l = (__bf16)(f - (float)p.h);
    return p;
}

// ---------------- prep: split + fragment-pack W into workspace ----------------
// frag tid = (((L*8+kc)*4+ot)*2+hi)*32+lane ; elems = W[L][ot*32+lane][kc*16+hi*8+e]
__global__ __launch_bounds__(256) void prep_w(
    const float* __restrict__ Wg, const float* __restrict__ Wd1,
    __bf16* __restrict__ ws)
{
    const int tid  = blockIdx.x * 256 + threadIdx.x;   // 0..8191
    const int lane = tid & 31;
    const int hi   = (tid >> 5) & 1;
    const int ot   = (tid >> 6) & 3;
    const int kc   = (tid >> 8) & 7;
    const int L    = tid >> 11;
    const float* src = ((L < 3) ? (Wg + L * 16384) : Wd1)
                     + (ot * 32 + lane) * 128 + kc * 16 + hi * 8;
    const f32x4 v0 = *(const f32x4*)(src);
    const f32x4 v1 = *(const f32x4*)(src + 4);
    bf16x8 h8, l8;
    #pragma unroll
    for (int e = 0; e < 4; ++e) {
        bfpair p0 = splitf(v0[e]); h8[e]   = p0.h; l8[e]   = p0.l;
        bfpair p1 = splitf(v1[e]); h8[4+e] = p1.h; l8[4+e] = p1.l;
    }
    ((bf16x8*)ws)[tid]        = h8;   // Ph
    ((bf16x8*)ws)[8192 + tid] = l8;   // Pl
}

// ------------------------------- main kernel -------------------------------
__global__ __launch_bounds__(128, 3) void mt_fwd(
    const float* __restrict__ q,   const float* __restrict__ Win, const float* __restrict__ bin,
    const float* __restrict__ bg,  const float* __restrict__ bd1,
    const float* __restrict__ Wd2, const float* __restrict__ bd2,
    const bf16x8* __restrict__ Ph, float* __restrict__ out)
{
    __shared__ __attribute__((aligned(16))) float hs[32 * QP];   // 27136 B

    const int t    = threadIdx.x;
    const int nt   = t >> 6;            // wave: node-tile 0/1
    const int l    = t & 63;
    const int lane = l & 31;
    const int hi   = l >> 5;
    const int n    = nt * 32 + lane;    // this lane's node (col in D)
    const int nc   = (n < 52) ? n : 0;
    const int samp = blockIdx.x;
    const bf16x8* Pl = Ph + 8192;

    // LDS dword bases
    const int wbase = n * 4 + hi * QP;       // D-quad writes: + (ot*8+2j)*QP
    const int rbase = nc * 4 + hi * 2 * QP;  // B-quad reads:  + (kc*4+d)*QP

    // ---- closed-form GCN neighbors (self + 2 lateral(dup x2) + <=2 chain) ----
    int nb[5]; float nw[5];
    {
        const int   fi = n >> 2, js = n & 3;
        const float dg = 5.f + (js > 0 ? 1.f : 0.f) + (js < 3 ? 1.f : 0.f);
        const float di = rsqrtf(dg);
        nb[0] = n;                          nw[0] = di * di;
        nb[1] = ((fi + 12) % 13) * 4 + js;  nw[1] = 2.f * di * di;
        nb[2] = ((fi + 1) % 13) * 4 + js;   nw[2] = 2.f * di * di;
        nb[3] = (js > 0) ? (n - 1) : 0;
        nw[3] = (js > 0) ? di * rsqrtf(6.f + (js > 1 ? 1.f : 0.f)) : 0.f;
        nb[4] = (js < 3) ? (n + 1) : 0;
        nw[4] = (js < 3) ? di * rsqrtf(6.f + (js < 2 ? 1.f : 0.f)) : 0.f;
        if (n >= 52) {
            #pragma unroll
            for (int c = 0; c < 5; ++c) { nb[c] = 0; nw[c] = 0.f; }
        }
    }
    int gb[5];
    #pragma unroll
    for (int c = 0; c < 5; ++c) gb[c] = nb[c] * 4 + hi * 2 * QP;

    bf16x8 bh[8], bl[8];   // persistent x state (B-frag layout, split)

    // ---------------- encoder: x0^T = relu(Win @ q^T + bin) ----------------
    {
        f32x4 z4; z4[0]=0.f; z4[1]=0.f; z4[2]=0.f; z4[3]=0.f;
        f32x4 u0 = z4, u1 = z4;
        if (hi == 0 && n < 52) {
            const float* qp = q + (samp * 52 + n) * 6;
            const f32x2 a = *(const f32x2*)(qp);
            const f32x2 b = *(const f32x2*)(qp + 2);
            const f32x2 c = *(const f32x2*)(qp + 4);
            u0[0]=a[0]; u0[1]=a[1]; u0[2]=b[0]; u0[3]=b[1]; u1[0]=c[0]; u1[1]=c[1];
        }
        bf16x8 qh, ql;
        #pragma unroll
        for (int e = 0; e < 4; ++e) {
            bfpair p0 = splitf(u0[e]); qh[e]   = p0.h; ql[e]   = p0.l;
            bfpair p1 = splitf(u1[e]); qh[4+e] = p1.h; ql[4+e] = p1.l;
        }

        #pragma unroll
        for (int ot = 0; ot < 4; ++ot) {
            f32x4 v0 = z4, v1 = z4;
            if (hi == 0) {
                const int o_r = ot * 32 + lane;
                const f32x2 a = *(const f32x2*)(Win + o_r * 6);
                const f32x2 b = *(const f32x2*)(Win + o_r * 6 + 2);
                const f32x2 c = *(const f32x2*)(Win + o_r * 6 + 4);
                v0[0]=a[0]; v0[1]=a[1]; v0[2]=b[0]; v0[3]=b[1]; v1[0]=c[0]; v1[1]=c[1];
            }
            bf16x8 ah, al;
            #pragma unroll
            for (int e = 0; e < 4; ++e) {
                bfpair p0 = splitf(v0[e]); ah[e]   = p0.h; al[e]   = p0.l;
                bfpair p1 = splitf(v1[e]); ah[4+e] = p1.h; al[4+e] = p1.l;
            }
            f32x16 acc;
            #pragma unroll
            for (int r = 0; r < 16; ++r) acc[r] = 0.f;
            acc = MFMA(ah, qh, acc);
            acc = MFMA(ah, ql, acc);
            acc = MFMA(al, qh, acc);
            if (n < 52) {
                #pragma unroll
                for (int j = 0; j < 4; ++j) {
                    const f32x4 bv = *(const f32x4*)(bin + ot * 32 + 8 * j + 4 * hi);
                    f32x4 v;
                    #pragma unroll
                    for (int e = 0; e < 4; ++e) v[e] = fmaxf(acc[4 * j + e] + bv[e], 0.f);
                    *(f32x4*)&hs[wbase + (ot * 8 + 2 * j) * QP] = v;
                }
            }
        }
    }
    __syncthreads();
    // read back x0 in B-frag layout, split into bh/bl
    #pragma unroll
    for (int kc = 0; kc < 8; ++kc) {
        const f32x4 a0 = *(const f32x4*)&hs[rbase + (kc * 4 + 0) * QP];
        const f32x4 a1 = *(const f32x4*)&hs[rbase + (kc * 4 + 1) * QP];
        #pragma unroll
        for (int e = 0; e < 4; ++e) {
            bfpair p0 = splitf(a0[e]); bh[kc][e]   = p0.h; bl[kc][e]   = p0.l;
            bfpair p1 = splitf(a1[e]); bh[kc][4+e] = p1.h; bl[kc][4+e] = p1.l;
        }
    }
    __syncthreads();

    // ------------------- 3 GNN layers -------------------
    #pragma unroll 1
    for (int L = 0; L < 3; ++L) {
        const int fbase = L * 2048 + hi * 32 + lane;

        // ---- h = x @ W^T (MFMA, 3-pass split), ot-pairs to cap reg pressure ----
        #pragma unroll
        for (int op = 0; op < 2; ++op) {
            f32x16 acc0, acc1;
            #pragma unroll
            for (int r = 0; r < 16; ++r) { acc0[r] = 0.f; acc1[r] = 0.f; }
            #pragma unroll
            for (int kc = 0; kc < 8; ++kc) {
                const int fk = fbase + kc * 256 + op * 128;
                const bf16x8 wh0 = Ph[fk];
                const bf16x8 wl0 = Pl[fk];
                const bf16x8 wh1 = Ph[fk + 64];
                const bf16x8 wl1 = Pl[fk + 64];
                acc0 = MFMA(wh0, bh[kc], acc0);
                acc1 = MFMA(wh1, bh[kc], acc1);
                acc0 = MFMA(wh0, bl[kc], acc0);
                acc1 = MFMA(wh1, bl[kc], acc1);
                acc0 = MFMA(wl0, bh[kc], acc0);
                acc1 = MFMA(wl1, bh[kc], acc1);
            }
            if (n < 52) {
                #pragma unroll
                for (int j = 0; j < 4; ++j) {
                    f32x4 v0 = { acc0[4*j+0], acc0[4*j+1], acc0[4*j+2], acc0[4*j+3] };
                    f32x4 v1 = { acc1[4*j+0], acc1[4*j+1], acc1[4*j+2], acc1[4*j+3] };
                    *(f32x4*)&hs[wbase + ((2*op)   * 8 + 2 * j) * QP] = v0;
                    *(f32x4*)&hs[wbase + ((2*op+1) * 8 + 2 * j) * QP] = v1;
                }
            }
        }
        __syncthreads();

        // ---- fused gather t = A@h + epilogue x += relu(t+b), per kc ----
        const float* bsrc = bg + L * 128;
        #pragma unroll
        for (int kc = 0; kc < 8; ++kc) {
            f32x4 t0, t1;
            #pragma unroll
            for (int e = 0; e < 4; ++e) { t0[e] = 0.f; t1[e] = 0.f; }
            #pragma unroll
            for (int c = 0; c < 5; ++c) {
                const f32x4 r0 = *(const f32x4*)&hs[gb[c] + (kc * 4 + 0) * QP];
                const f32x4 r1 = *(const f32x4*)&hs[gb[c] + (kc * 4 + 1) * QP];
                t0 += nw[c] * r0;
                t1 += nw[c] * r1;
            }
            const int f0 = kc * 16 + 8 * hi;
            const f32x4 b0 = *(const f32x4*)(bsrc + f0);
            const f32x4 b1 = *(const f32x4*)(bsrc + f0 + 4);
            #pragma unroll
            for (int e = 0; e < 4; ++e) {
                {
                    const float xo = (float)bh[kc][e] + (float)bl[kc][e];
                    const float xn = xo + fmaxf(t0[e] + b0[e], 0.f);
                    bfpair p = splitf(xn); bh[kc][e] = p.h; bl[kc][e] = p.l;
                }
                {
                    const float xo = (float)bh[kc][4+e] + (float)bl[kc][4+e];
                    const float xn = xo + fmaxf(t1[e] + b1[e], 0.f);
                    bfpair p = splitf(xn); bh[kc][4+e] = p.h; bl[kc][4+e] = p.l;
                }
            }
        }
        __syncthreads();   // gather reads done before next layer's h writes
    }

    // ---------------- decoder-1: y = relu(x @ Wd1^T + bd1), bounce to B-frag ----------------
    {
        const int fbase = 3 * 2048 + hi * 32 + lane;
        #pragma unroll
        for (int op = 0; op < 2; ++op) {
            f32x16 acc0, acc1;
            #pragma unroll
            for (int r = 0; r < 16; ++r) { acc0[r] = 0.f; acc1[r] = 0.f; }
            #pragma unroll
            for (int kc = 0; kc < 8; ++kc) {
                const int fk = fbase + kc * 256 + op * 128;
                const bf16x8 wh0 = Ph[fk];
                const bf16x8 wl0 = Pl[fk];
                const bf16x8 wh1 = Ph[fk + 64];
                const bf16x8 wl1 = Pl[fk + 64];
                acc0 = MFMA(wh0, bh[kc], acc0);
                acc1 = MFMA(wh1, bh[kc], acc1);
                acc0 = MFMA(wh0, bl[kc], acc0);
                acc1 = MFMA(wh1, bl[kc], acc1);
                acc0 = MFMA(wl0, bh[kc], acc0);
                acc1 = MFMA(wl1, bh[kc], acc1);
            }
            if (n < 52) {
                #pragma unroll
                for (int j = 0; j < 4; ++j) {
                    const f32x4 bv0 = *(const f32x4*)(bd1 + (2*op)   * 32 + 8 * j + 4 * hi);
                    const f32x4 bv1 = *(const f32x4*)(bd1 + (2*op+1) * 32 + 8 * j + 4 * hi);
                    f32x4 v0, v1;
                    #pragma unroll
                    for (int e = 0; e < 4; ++e) {
                        v0[e] = fmaxf(acc0[4 * j + e] + bv0[e], 0.f);
                        v1[e] = fmaxf(acc1[4 * j + e] + bv1[e], 0.f);
                    }
                    *(f32x4*)&hs[wbase + ((2*op)   * 8 + 2 * j) * QP] = v0;
                    *(f32x4*)&hs[wbase + ((2*op+1) * 8 + 2 * j) * QP] = v1;
                }
            }
        }
        __syncthreads();
        #pragma unroll
        for (int kc = 0; kc < 8; ++kc) {
            const f32x4 a0 = *(const f32x4*)&hs[rbase + (kc * 4 + 0) * QP];
            const f32x4 a1 = *(const f32x4*)&hs[rbase + (kc * 4 + 1) * QP];
            #pragma unroll
            for (int e = 0; e < 4; ++e) {
                bfpair p0 = splitf(a0[e]); bh[kc][e]   = p0.h; bl[kc][e]   = p0.l;
                bfpair p1 = splitf(a1[e]); bh[kc][4+e] = p1.h; bl[kc][4+e] = p1.l;
            }
        }
    }

    // ---------------- decoder-2: out^T = Wd2 @ y^T + bd2 ----------------
    {
        f32x16 acc;
        #pragma unroll
        for (int r = 0; r < 16; ++r) acc[r] = 0.f;
        f32x4 z4; z4[0]=0.f; z4[1]=0.f; z4[2]=0.f; z4[3]=0.f;

        #pragma unroll
        for (int kc = 0; kc < 8; ++kc) {
            const int kb = kc * 16 + 8 * hi;
            f32x4 w0 = z4, w1 = z4;
            if (lane < 6) {
                const float* wp = Wd2 + lane * 128 + kb;
                w0 = *(const f32x4*)(wp);
                w1 = *(const f32x4*)(wp + 4);
            }
            bf16x8 ah, al;
            #pragma unroll
            for (int e = 0; e < 4; ++e) {
                bfpair p0 = splitf(w0[e]); ah[e]   = p0.h; al[e]   = p0.l;
                bfpair p1 = splitf(w1[e]); ah[4+e] = p1.h; al[4+e] = p1.l;
            }
            acc = MFMA(ah, bh[kc], acc);
            acc = MFMA(ah, bl[kc], acc);
            acc = MFMA(al, bh[kc], acc);
        }
        if (n < 52) {
            float* op = out + (samp * 52 + n) * 6;
            if (hi == 0) {
                #pragma unroll
                for (int r = 0; r < 4; ++r) op[r] = acc[r] + bd2[r];          // f = r
            } else {
                #pragma unroll
                for (int r = 0; r < 2; ++r) op[4 + r] = acc[r] + bd2[4 + r];  // f = 4+r
            }
        }
    }
}

extern "C" void kernel_launch(void* const* d_in, const int* in_sizes, int n_in,
                              void* d_out, int out_size, void* d_ws, size_t ws_size,
                              hipStream_t stream) {
    (void)in_sizes; (void)n_in; (void)ws_size; (void)out_size;
    const float* q   = (const float*)d_in[0];
    const float* Win = (const float*)d_in[1];
    const float* bin = (const float*)d_in[2];
    const float* Wg  = (const float*)d_in[3];
    const float* bg  = (const float*)d_in[4];
    const float* Wd1 = (const float*)d_in[5];
    const float* bd1 = (const float*)d_in[6];
    const float* Wd2 = (const float*)d_in[7];
    const float* bd2 = (const float*)d_in[8];
    float* out = (float*)d_out;

    prep_w<<<32, 256, 0, stream>>>(Wg, Wd1, (__bf16*)d_ws);
    mt_fwd<<<4096, 128, 0, stream>>>(q, Win, bin, bg, bd1, Wd2, bd2,
                                     (const bf16x8*)d_ws, out);
}